// Round 1
// baseline (469.232 us; speedup 1.0000x reference)
//
#include <hip/hip_runtime.h>
#include <hip/hip_bf16.h>
#include <math.h>

#define DEVI __device__ __forceinline__

typedef __attribute__((ext_vector_type(8))) short bf16x8;   // 8 bf16 in 4 VGPRs
typedef __attribute__((ext_vector_type(4))) float f32x4;

constexpr int Bn = 2;
constexpr int Tn = 2048;
constexpr int Cn = 2048;
constexpr int Hn = 16;
constexpr int Dn = 128;
constexpr int Mrows = Bn * Tn;   // 4096
constexpr int Nqkv = 3 * Cn;     // 6144
constexpr int BH = Bn * Hn;      // 32
constexpr int NKT = Cn / 32;     // 64 K-tiles (BK=32) per GEMM

DEVI f32x4 mfma16x16(bf16x8 a, bf16x8 b, f32x4 c) {
    return __builtin_amdgcn_mfma_f32_16x16x32_bf16(a, b, c, 0, 0, 0);
}

DEVI bf16x8 load8(const __hip_bfloat16* p) {
    return *(const bf16x8*)p;   // 16B aligned at all call sites
}

DEVI short bf16bits(float f) {
    union { __hip_bfloat16 b; short s; } u;
    u.b = __float2bfloat16(f);
    return u.s;
}

// Async global->LDS 16B per lane. LDS dest is wave-uniform base + lane*16.
typedef const __attribute__((address_space(1))) void* gas1_t;
typedef __attribute__((address_space(3))) void* las3_t;
DEVI void stage16(const __hip_bfloat16* g, __hip_bfloat16* l) {
    __builtin_amdgcn_global_load_lds((gas1_t)g, (las3_t)l, 16, 0, 0);
}

// LDS byte-offset swizzle for 64B-row tiles (BK=32 bf16).
// Flips byte bits 4,5 keyed on row bits 1,3 -> 16-lane column read goes
// 8-way -> 2-way bank aliasing (free, m136). Involution; preserves 16B
// contiguity (only bits >=4 touched), so global_load_lds linear-dest +
// inverse-swizzled source + swizzled ds_read is exact (rule 21).
DEVI int swzb(int o) {
    return o ^ (((o >> 9) & 1) << 5) ^ (((o >> 7) & 1) << 4);
}

DEVI bf16x8 lds8(const short* tile, int off) {
    return *(const bf16x8*)((const char*)tile + off);
}

// ---------------------------------------------------------------------------
// fp32 -> bf16 bulk convert: 8 elements/thread, n % 2048 == 0.
// ---------------------------------------------------------------------------
__global__ __launch_bounds__(256) void cvt_kernel(
    const float* __restrict__ src, __hip_bfloat16* __restrict__ dst)
{
    const size_t i8 = ((size_t)blockIdx.x * 256 + threadIdx.x) * 8;
    const float4 a = *(const float4*)(src + i8);
    const float4 b = *(const float4*)(src + i8 + 4);
    union { bf16x8 v; __hip_bfloat16 h[8]; } u;
    u.h[0] = __float2bfloat16(a.x); u.h[1] = __float2bfloat16(a.y);
    u.h[2] = __float2bfloat16(a.z); u.h[3] = __float2bfloat16(a.w);
    u.h[4] = __float2bfloat16(b.x); u.h[5] = __float2bfloat16(b.y);
    u.h[6] = __float2bfloat16(b.z); u.h[7] = __float2bfloat16(b.w);
    *(bf16x8*)(dst + i8) = u.v;
}

// ---------------------------------------------------------------------------
// QKV GEMM: 256x128 tile, BK=32, 8 waves (4 row-groups x 2 col-groups),
// TRIPLE-buffered LDS (72 KB -> 2 blocks/CU), phase-split schedule with
// counted s_waitcnt vmcnt(3) at tile boundaries (never 0 in steady state),
// st-swizzled LDS (2-way conflicts), s_setprio around MFMA clusters,
// XCD-bijective block swizzle (768 % 8 == 0).
// Prefetch distance = 2 K-tiles: stage of tile t+2 -> buf (t+2)%3 while
// reading buf t%3; buf (t+2)%3's last reader was tile t-1, which completed
// before the barrier that precedes these stage issues (WAR-safe); RAW is
// per-thread vmcnt(3) drain + barrier + memory-fence asm.
// ---------------------------------------------------------------------------
__global__ __launch_bounds__(512, 4) void qkv_gemm_kernel(
    const __hip_bfloat16* __restrict__ xb,
    const __hip_bfloat16* __restrict__ wab,
    const float* __restrict__ bias,
    __hip_bfloat16* __restrict__ Qo,
    __hip_bfloat16* __restrict__ Ko,
    __hip_bfloat16* __restrict__ Vt)
{
    __shared__ __align__(16) short As[3][256 * 32];   // 3 x 16 KB
    __shared__ __align__(16) short Bs[3][128 * 32];   // 3 x  8 KB
    const int tid  = threadIdx.x;
    const int lane = tid & 63;
    const int wid  = tid >> 6;          // 0..7
    const int quad = lane >> 4;         // 0..3
    const int l16  = lane & 15;

    // XCD-bijective swizzle over 768 blocks (48 n-blocks x 16 m-blocks).
    const int wg = (blockIdx.x & 7) * 96 + (blockIdx.x >> 3);
    const int bx = wg >> 4;             // 0..47  (n / 128)
    const int by = wg & 15;             // 0..15  (m / 256)
    const int bm = by * 256;
    const int bn = bx * 128;

    const int wr0 = (wid >> 1) * 64;    // wave row group within 256
    const int wc0 = (wid & 1) * 64;     // wave col group within 128

    // Staging: A tile 256x32 bf16 = 16 KB (2 loads/thread), B tile 128x32
    // = 8 KB (1 load/thread). Linear LDS dest o, global source at swzb(o).
    const int oA0 = tid * 16;
    const int oA1 = 8192 + tid * 16;
    const int oB0 = tid * 16;
    const int sA0 = swzb(oA0), sA1 = swzb(oA1), sB0 = swzb(oB0);
    const __hip_bfloat16* Ag0 = xb  + (size_t)(bm + (sA0 >> 6)) * Cn + ((sA0 & 63) >> 1);
    const __hip_bfloat16* Ag1 = xb  + (size_t)(bm + (sA1 >> 6)) * Cn + ((sA1 & 63) >> 1);
    const __hip_bfloat16* Bg0 = wab + (size_t)(bn + (sB0 >> 6)) * Cn + ((sB0 & 63) >> 1);

    // Per-thread swizzled read offsets (constant across K-tiles).
    int offA[4], offB[4];
#pragma unroll
    for (int f = 0; f < 4; ++f) {
        offA[f] = swzb((wr0 + f * 16 + l16) * 64 + quad * 16);
        offB[f] = swzb((wc0 + f * 16 + l16) * 64 + quad * 16);
    }

    const f32x4 zero = {0.f, 0.f, 0.f, 0.f};
    f32x4 acc[4][4];
#pragma unroll
    for (int i = 0; i < 4; ++i)
#pragma unroll
        for (int j = 0; j < 4; ++j) acc[i][j] = zero;

    // Prologue: stage tiles 0 and 1 (6 loads), drain tile 0 only (vmcnt 3).
    stage16(Ag0,      (__hip_bfloat16*)&As[0][oA0 >> 1]);
    stage16(Ag1,      (__hip_bfloat16*)&As[0][oA1 >> 1]);
    stage16(Bg0,      (__hip_bfloat16*)&Bs[0][oB0 >> 1]);
    stage16(Ag0 + 32, (__hip_bfloat16*)&As[1][oA0 >> 1]);
    stage16(Ag1 + 32, (__hip_bfloat16*)&As[1][oA1 >> 1]);
    stage16(Bg0 + 32, (__hip_bfloat16*)&Bs[1][oB0 >> 1]);
    asm volatile("s_waitcnt vmcnt(3)" ::: "memory");
    __builtin_amdgcn_s_barrier();
    asm volatile("" ::: "memory");

    int cur = 0, pre = 2;
    for (int kt = 0; kt < NKT; ++kt) {
        const short* At = &As[cur][0];
        const short* Bt = &Bs[cur][0];
        const int kg = (kt + 2) * 32;
        // ---- phase 1: stage A(t+2) | read A frags + B frags 0,1 | 8 MFMA
        if (kt + 2 < NKT) {
            stage16(Ag0 + kg, (__hip_bfloat16*)&As[pre][oA0 >> 1]);
            stage16(Ag1 + kg, (__hip_bfloat16*)&As[pre][oA1 >> 1]);
        }
        bf16x8 a0 = lds8(At, offA[0]);
        bf16x8 a1 = lds8(At, offA[1]);
        bf16x8 a2 = lds8(At, offA[2]);
        bf16x8 a3 = lds8(At, offA[3]);
        bf16x8 b0 = lds8(Bt, offB[0]);
        bf16x8 b1 = lds8(Bt, offB[1]);
        __builtin_amdgcn_s_barrier();
        __builtin_amdgcn_s_setprio(1);
        acc[0][0] = mfma16x16(a0, b0, acc[0][0]);
        acc[1][0] = mfma16x16(a1, b0, acc[1][0]);
        acc[2][0] = mfma16x16(a2, b0, acc[2][0]);
        acc[3][0] = mfma16x16(a3, b0, acc[3][0]);
        acc[0][1] = mfma16x16(a0, b1, acc[0][1]);
        acc[1][1] = mfma16x16(a1, b1, acc[1][1]);
        acc[2][1] = mfma16x16(a2, b1, acc[2][1]);
        acc[3][1] = mfma16x16(a3, b1, acc[3][1]);
        __builtin_amdgcn_s_setprio(0);
        __builtin_amdgcn_s_barrier();
        // ---- phase 2: stage B(t+2) | read B frags 2,3 | 8 MFMA
        if (kt + 2 < NKT)
            stage16(Bg0 + kg, (__hip_bfloat16*)&Bs[pre][oB0 >> 1]);
        bf16x8 b2 = lds8(Bt, offB[2]);
        bf16x8 b3 = lds8(Bt, offB[3]);
        __builtin_amdgcn_s_barrier();
        __builtin_amdgcn_s_setprio(1);
        acc[0][2] = mfma16x16(a0, b2, acc[0][2]);
        acc[1][2] = mfma16x16(a1, b2, acc[1][2]);
        acc[2][2] = mfma16x16(a2, b2, acc[2][2]);
        acc[3][2] = mfma16x16(a3, b2, acc[3][2]);
        acc[0][3] = mfma16x16(a0, b3, acc[0][3]);
        acc[1][3] = mfma16x16(a1, b3, acc[1][3]);
        acc[2][3] = mfma16x16(a2, b3, acc[2][3]);
        acc[3][3] = mfma16x16(a3, b3, acc[3][3]);
        __builtin_amdgcn_s_setprio(0);
        // Tile boundary: counted drain — tile t+1 landed, t+2 (3 loads)
        // stays in flight. Tail drains to 0.
        if (kt < NKT - 2) {
            asm volatile("s_waitcnt vmcnt(3)" ::: "memory");
        } else {
            asm volatile("s_waitcnt vmcnt(0)" ::: "memory");
        }
        __builtin_amdgcn_s_barrier();
        asm volatile("" ::: "memory");
        cur = (cur == 2) ? 0 : cur + 1;
        pre = (pre == 2) ? 0 : pre + 1;
    }

    // Epilogue: scatter to Q[b,h,t,d], K[b,h,t,d], Vt[b,h,d,t].
#pragma unroll
    for (int j = 0; j < 4; ++j) {
        const int n = bn + wc0 + j * 16 + l16;
        const float bv = bias[n];
        const int sel = n >> 11;      // 0=q, 1=k, 2=v
        const int c   = n & 2047;
        const int h   = c >> 7;
        const int d   = c & 127;
#pragma unroll
        for (int i = 0; i < 4; ++i) {
#pragma unroll
            for (int r = 0; r < 4; ++r) {
                const int m = bm + wr0 + i * 16 + quad * 4 + r;
                const int b = m >> 11;
                const int t = m & 2047;
                const int bh = b * Hn + h;
                const __hip_bfloat16 hv = __float2bfloat16(acc[i][j][r] + bv);
                if (sel == 0)      Qo[((size_t)bh * Tn + t) * Dn + d] = hv;
                else if (sel == 1) Ko[((size_t)bh * Tn + t) * Dn + d] = hv;
                else               Vt[((size_t)bh * Dn + d) * Tn + t] = hv;
            }
        }
    }
}

// ---------------------------------------------------------------------------
// RoPE in place on Q and K.
// ---------------------------------------------------------------------------
__global__ __launch_bounds__(256) void rope_kernel(
    __hip_bfloat16* __restrict__ Qo,
    __hip_bfloat16* __restrict__ Ko)
{
    const size_t idx = (size_t)blockIdx.x * blockDim.x + threadIdx.x; // BH*T*64
    const int d2 = (int)(idx & 63);
    const int t  = (int)((idx >> 6) & (size_t)(Tn - 1));
    const float inv = exp2f(-(float)d2 * (1.0f / 64.0f) * 13.287712379549449f);
    float sn, cs;
    sincosf((float)t * inv, &sn, &cs);
    const size_t base = (idx >> 6) * (size_t)Dn + (size_t)(2 * d2);
    {
        const float a = __bfloat162float(Qo[base]);
        const float b = __bfloat162float(Qo[base + 1]);
        Qo[base]     = __float2bfloat16(a * cs - b * sn);
        Qo[base + 1] = __float2bfloat16(a * sn + b * cs);
    }
    {
        const float a = __bfloat162float(Ko[base]);
        const float b = __bfloat162float(Ko[base + 1]);
        Ko[base]     = __float2bfloat16(a * cs - b * sn);
        Ko[base + 1] = __float2bfloat16(a * sn + b * cs);
    }
}

// ---------------------------------------------------------------------------
// Flash attention (causal), GEMM-style LDS staging (passed round 10).
// ---------------------------------------------------------------------------
__global__ __launch_bounds__(256) void flash_kernel(
    const __hip_bfloat16* __restrict__ Qo,
    const __hip_bfloat16* __restrict__ Ko,
    const __hip_bfloat16* __restrict__ Vt,
    __hip_bfloat16* __restrict__ Y)
{
    __shared__ __align__(16) short Ks[2][32 * 136];  // 17.0 KB
    __shared__ __align__(16) short Vs[2][128 * 40];  // 20.0 KB
    __shared__ __align__(16) short Ps[4][16 * 40];   //  5.0 KB wave-private P
    const int tid  = threadIdx.x;
    const int lane = tid & 63;
    const int wid  = tid >> 6;
    const int quad = lane >> 4;
    const int l16  = lane & 15;
    const int bh   = blockIdx.x & (BH - 1);
    const int qblk = 31 - (blockIdx.x >> 5);         // heavy q-blocks first
    const int q0w  = qblk * 64 + wid * 16;
    const int nkt  = 2 * qblk + 2;

    const __hip_bfloat16* Qb = Qo + (size_t)bh * Tn * Dn;
    const __hip_bfloat16* Kg = Ko + (size_t)bh * Tn * Dn;   // [t][d]
    const __hip_bfloat16* Vg = Vt + (size_t)bh * Dn * Tn;   // [d][t]
    short* P = &Ps[wid][0];

    const int krow = tid >> 3, kseg = tid & 7;
    const int vrow = tid >> 1, vseg = tid & 1;
    const __hip_bfloat16* KgT = Kg + (size_t)krow * Dn + kseg * 16;
    const __hip_bfloat16* VgT = Vg + (size_t)vrow * Tn + vseg * 16;
    short* KsT = (short*)&Ks[0][krow * 136 + kseg * 16];
    short* VsT = (short*)&Vs[0][vrow * 40 + vseg * 16];
    const int KsBuf = 32 * 136, VsBuf = 128 * 40;

    bf16x8 qf[4];
#pragma unroll
    for (int ks = 0; ks < 4; ++ks)
        qf[ks] = load8(Qb + (size_t)(q0w + l16) * Dn + ks * 32 + quad * 8);

    const f32x4 zero = {0.f, 0.f, 0.f, 0.f};
    f32x4 o[8];
#pragma unroll
    for (int j = 0; j < 8; ++j) o[j] = zero;
    float lpart[4] = {0.f, 0.f, 0.f, 0.f};
    const float scale2 = 0.12751743430267602f;   // log2(e)/sqrt(128)

    *(bf16x8*)(KsT)     = load8((const __hip_bfloat16*)KgT);
    *(bf16x8*)(KsT + 8) = load8((const __hip_bfloat16*)KgT + 8);
    *(bf16x8*)(VsT)     = load8((const __hip_bfloat16*)VgT);
    *(bf16x8*)(VsT + 8) = load8((const __hip_bfloat16*)VgT + 8);
    __syncthreads();

    for (int kt = 0; kt < nkt; ++kt) {
        const int cur = kt & 1;
        if (kt + 1 < nkt) {
            const int kb2 = (kt + 1) * 32;
            const int nxt = (cur ^ 1);
            *(bf16x8*)(KsT + nxt * KsBuf)     = load8((const __hip_bfloat16*)KgT + (size_t)kb2 * Dn);
            *(bf16x8*)(KsT + nxt * KsBuf + 8) = load8((const __hip_bfloat16*)KgT + (size_t)kb2 * Dn + 8);
            *(bf16x8*)(VsT + nxt * VsBuf)     = load8((const __hip_bfloat16*)VgT + kb2);
            *(bf16x8*)(VsT + nxt * VsBuf + 8) = load8((const __hip_bfloat16*)VgT + kb2 + 8);
        }
        const int kb = kt * 32;
        if (kb <= q0w + 15) {
            f32x4 sc0 = zero, sc1 = zero;
#pragma unroll
            for (int ks = 0; ks < 4; ++ks) {
                bf16x8 kf0 = *(const bf16x8*)&Ks[cur][(l16) * 136 + ks * 32 + quad * 8];
                bf16x8 kf1 = *(const bf16x8*)&Ks[cur][(16 + l16) * 136 + ks * 32 + quad * 8];
                sc0 = mfma16x16(qf[ks], kf0, sc0);
                sc1 = mfma16x16(qf[ks], kf1, sc1);
            }
            if (kb + 31 <= q0w) {
#pragma unroll
                for (int r = 0; r < 4; ++r) {
                    const float p0 = exp2f(sc0[r] * scale2);
                    const float p1 = exp2f(sc1[r] * scale2);
                    lpart[r] += p0 + p1;
                    P[(quad * 4 + r) * 40 + l16]      = bf16bits(p0);
                    P[(quad * 4 + r) * 40 + 16 + l16] = bf16bits(p1);
                }
            } else {
#pragma unroll
                for (int r = 0; r < 4; ++r) {
                    const int row = q0w + quad * 4 + r;
                    const float a0 = (kb + l16      <= row) ? sc0[r] * scale2 : -INFINITY;
                    const float a1 = (kb + 16 + l16 <= row) ? sc1[r] * scale2 : -INFINITY;
                    const float p0 = exp2f(a0);
                    const float p1 = exp2f(a1);
                    lpart[r] += p0 + p1;
                    P[(quad * 4 + r) * 40 + l16]      = bf16bits(p0);
                    P[(quad * 4 + r) * 40 + 16 + l16] = bf16bits(p1);
                }
            }
            __builtin_amdgcn_sched_barrier(0);
            const bf16x8 af = *(const bf16x8*)(P + l16 * 40 + quad * 8);
#pragma unroll
            for (int j = 0; j < 8; ++j) {
                bf16x8 vf = *(const bf16x8*)&Vs[cur][(j * 16 + l16) * 40 + quad * 8];
                o[j] = mfma16x16(af, vf, o[j]);
            }
            __builtin_amdgcn_sched_barrier(0);
        }
        __syncthreads();
    }

    float invl[4];
#pragma unroll
    for (int r = 0; r < 4; ++r) {
        float s = lpart[r];
#pragma unroll
        for (int off = 1; off < 16; off <<= 1)
            s += __shfl_xor(s, off, 16);
        invl[r] = 1.0f / s;
    }

    const int b = bh >> 4;
    const int h = bh & 15;
#pragma unroll
    for (int j = 0; j < 8; ++j) {
#pragma unroll
        for (int r = 0; r < 4; ++r) {
            const int t = q0w + quad * 4 + r;
            Y[((size_t)b * Tn + t) * Cn + h * Dn + j * 16 + l16] =
                __float2bfloat16(o[j][r] * invl[r]);
        }
    }
}

// ---------------------------------------------------------------------------
// Output projection, pure bf16 inputs, global_load_lds staging, dbuf.
// out = Yb @ wpb^T + b_proj (fp32 out).
// ---------------------------------------------------------------------------
__global__ __launch_bounds__(256) void proj_gemm_kernel(
    const __hip_bfloat16* __restrict__ Yb,
    const __hip_bfloat16* __restrict__ wpb,
    const float* __restrict__ bias,
    float* __restrict__ out)
{
    __shared__ __align__(16) __hip_bfloat16 As[2][128 * 32];
    __shared__ __align__(16) __hip_bfloat16 Bs[2][128 * 32];
    const int tid  = threadIdx.x;
    const int lane = tid & 63;
    const int wid  = tid >> 6;
    const int quad = lane >> 4;
    const int l16  = lane & 15;
    const int bm = blockIdx.y * 128;
    const int bn = blockIdx.x * 128;
    const int wm = (wid >> 1) * 64;
    const int wn = (wid & 1) * 64;

    const int lr = lane >> 2;
    const int lc = (lane & 3) * 8;
    const int r0 = 32 * wid;
    const __hip_bfloat16* Ag0 = Yb  + (size_t)(bm + r0 + lr) * Cn + lc;
    const __hip_bfloat16* Ag1 = Yb  + (size_t)(bm + r0 + 16 + lr) * Cn + lc;
    const __hip_bfloat16* Bg0 = wpb + (size_t)(bn + r0 + lr) * Cn + lc;
    const __hip_bfloat16* Bg1 = wpb + (size_t)(bn + r0 + 16 + lr) * Cn + lc;
    const int lbase0 = r0 * 32 + lane * 8;
    const int lbase1 = (r0 + 16) * 32 + lane * 8;

    const f32x4 zero = {0.f, 0.f, 0.f, 0.f};
    f32x4 acc[4][4];
#pragma unroll
    for (int i = 0; i < 4; ++i)
#pragma unroll
        for (int j = 0; j < 4; ++j) acc[i][j] = zero;

    stage16(Ag0, &As[0][lbase0]);
    stage16(Ag1, &As[0][lbase1]);
    stage16(Bg0, &Bs[0][lbase0]);
    stage16(Bg1, &Bs[0][lbase1]);
    __syncthreads();

    for (int kt = 0; kt < NKT; ++kt) {
        const int cur = kt & 1;
        if (kt + 1 < NKT) {
            const int kn = (kt + 1) * 32;
            stage16(Ag0 + kn, &As[cur ^ 1][lbase0]);
            stage16(Ag1 + kn, &As[cur ^ 1][lbase1]);
            stage16(Bg0 + kn, &Bs[cur ^ 1][lbase0]);
            stage16(Bg1 + kn, &Bs[cur ^ 1][lbase1]);
        }
        bf16x8 af[4], bfr[4];
#pragma unroll
        for (int i = 0; i < 4; ++i)
            af[i] = load8(&As[cur][(wm + i * 16 + l16) * 32 + quad * 8]);
#pragma unroll
        for (int j = 0; j < 4; ++j)
            bfr[j] = load8(&Bs[cur][(wn + j * 16 + l16) * 32 + quad * 8]);
#pragma unroll
        for (int i = 0; i < 4; ++i)
#pragma unroll
            for (int j = 0; j < 4; ++j)
                acc[i][j] = mfma16x16(af[i], bfr[j], acc[i][j]);
        __syncthreads();
    }

#pragma unroll
    for (int j = 0; j < 4; ++j) {
        const int n = bn + wn + j * 16 + l16;
        const float bv = bias[n];
#pragma unroll
        for (int i = 0; i < 4; ++i) {
#pragma unroll
            for (int r = 0; r < 4; ++r) {
                const int m = bm + wm + i * 16 + quad * 4 + r;
                out[(size_t)m * Cn + n] = acc[i][j][r] + bv;   // fp32 store
            }
        }
    }
}

// ---------------------------------------------------------------------------
extern "C" void kernel_launch(void* const* d_in, const int* in_sizes, int n_in,
                              void* d_out, int out_size, void* d_ws, size_t ws_size,
                              hipStream_t stream)
{
    // All five inputs AND the output are fp32 (verified round 5).
    const float* x      = (const float*)d_in[0];
    const float* w_att  = (const float*)d_in[1];
    const float* b_att  = (const float*)d_in[2];
    const float* w_proj = (const float*)d_in[3];
    const float* b_proj = (const float*)d_in[4];
    float* out = (float*)d_out;

    // Workspace layout (bf16 elements), ~96 MB total:
    //   [Qo per][Ko per][Vt per][xb per | Yb alias][wab 12.58M][wpb 4.19M]
    const size_t per  = (size_t)BH * Tn * Dn;        // 8,388,608
    const size_t wabN = (size_t)Nqkv * Cn;           // 12,582,912
    __hip_bfloat16* Qo  = (__hip_bfloat16*)d_ws;
    __hip_bfloat16* Ko  = Qo + per;
    __hip_bfloat16* Vt  = Ko + per;
    __hip_bfloat16* xb  = Vt + per;
    __hip_bfloat16* wab = xb + per;
    __hip_bfloat16* wpb = wab + wabN;
    __hip_bfloat16* Yb  = xb;                        // alias (see above)

    dim3 blk(256);
    cvt_kernel<<<dim3((Mrows * Cn) / 2048), blk, 0, stream>>>(x, xb);
    cvt_kernel<<<dim3((Nqkv * Cn) / 2048), blk, 0, stream>>>(w_att, wab);
    cvt_kernel<<<dim3((Cn * Cn) / 2048), blk, 0, stream>>>(w_proj, wpb);
    qkv_gemm_kernel<<<dim3((Mrows / 256) * (Nqkv / 128)), dim3(512), 0, stream>>>(
        xb, wab, b_att, Qo, Ko, Vt);
    rope_kernel<<<dim3((BH * Tn * 64) / 256), blk, 0, stream>>>(Qo, Ko);
    flash_kernel<<<dim3((Tn / 64) * BH), blk, 0, stream>>>(Qo, Ko, Vt, Yb);
    proj_gemm_kernel<<<dim3(Cn / 128, Mrows / 128), blk, 0, stream>>>(
        Yb, wpb, b_proj, out);
}

// Round 2
// 432.893 us; speedup vs baseline: 1.0839x; 1.0839x over previous
//
#include <hip/hip_runtime.h>
#include <hip/hip_bf16.h>
#include <math.h>

#define DEVI __device__ __forceinline__

typedef __attribute__((ext_vector_type(8))) short bf16x8;   // 8 bf16 in 4 VGPRs
typedef __attribute__((ext_vector_type(4))) float f32x4;

constexpr int Bn = 2;
constexpr int Tn = 2048;
constexpr int Cn = 2048;
constexpr int Hn = 16;
constexpr int Dn = 128;
constexpr int Mrows = Bn * Tn;   // 4096
constexpr int Nqkv = 3 * Cn;     // 6144
constexpr int BH = Bn * Hn;      // 32
constexpr int NKT = Cn / 32;     // 64 K-tiles per GEMM

DEVI f32x4 mfma16x16(bf16x8 a, bf16x8 b, f32x4 c) {
    return __builtin_amdgcn_mfma_f32_16x16x32_bf16(a, b, c, 0, 0, 0);
}

DEVI bf16x8 load8(const __hip_bfloat16* p) {
    return *(const bf16x8*)p;   // 16B aligned at all call sites
}

DEVI short bf16bits(float f) {
    union { __hip_bfloat16 b; short s; } u;
    u.b = __float2bfloat16(f);
    return u.s;
}

// Async global->LDS 16B per lane. Lane i of the wave deposits its 16B at
// lds_base + i*16B (wave-uniform base + lane*size semantics); pass the
// per-lane address matching that layout.
typedef const __attribute__((address_space(1))) void* gas1_t;
typedef __attribute__((address_space(3))) void* las3_t;
DEVI void stage16(const __hip_bfloat16* g, __hip_bfloat16* l) {
    __builtin_amdgcn_global_load_lds((gas1_t)g, (las3_t)l, 16, 0, 0);
}

DEVI bf16x8 lds8(const short* tile, int byte_off) {
    return *(const bf16x8*)((const char*)tile + byte_off);
}

// ---------------------------------------------------------------------------
// fp32 -> bf16 bulk convert: 8 elements/thread, n % 2048 == 0.
// ---------------------------------------------------------------------------
__global__ __launch_bounds__(256) void cvt_kernel(
    const float* __restrict__ src, __hip_bfloat16* __restrict__ dst)
{
    const size_t i8 = ((size_t)blockIdx.x * 256 + threadIdx.x) * 8;
    const float4 a = *(const float4*)(src + i8);
    const float4 b = *(const float4*)(src + i8 + 4);
    union { bf16x8 v; __hip_bfloat16 h[8]; } u;
    u.h[0] = __float2bfloat16(a.x); u.h[1] = __float2bfloat16(a.y);
    u.h[2] = __float2bfloat16(a.z); u.h[3] = __float2bfloat16(a.w);
    u.h[4] = __float2bfloat16(b.x); u.h[5] = __float2bfloat16(b.y);
    u.h[6] = __float2bfloat16(b.z); u.h[7] = __float2bfloat16(b.w);
    *(bf16x8*)(dst + i8) = u.v;
}

// ---------------------------------------------------------------------------
// QKV GEMM, pure bf16, m97-style global_load_lds staging, double-buffered.
// (Reverted to round-0 version: 163 us measured. Round-1's pseudo-8-phase
// rebuild regressed to 192 us — 4 barriers/K-tile + worse L2 mapping.)
// ---------------------------------------------------------------------------
__global__ __launch_bounds__(256) void qkv_gemm_kernel(
    const __hip_bfloat16* __restrict__ xb,
    const __hip_bfloat16* __restrict__ wab,
    const float* __restrict__ bias,
    __hip_bfloat16* __restrict__ Qo,
    __hip_bfloat16* __restrict__ Ko,
    __hip_bfloat16* __restrict__ Vt)
{
    __shared__ __align__(16) __hip_bfloat16 As[2][128 * 32];  // 2 x 8 KB
    __shared__ __align__(16) __hip_bfloat16 Bs[2][128 * 32];  // 2 x 8 KB
    const int tid  = threadIdx.x;
    const int lane = tid & 63;
    const int wid  = tid >> 6;
    const int quad = lane >> 4;
    const int l16  = lane & 15;
    const int bm = blockIdx.y * 128;
    const int bn = blockIdx.x * 128;
    const int wm = (wid >> 1) * 64;
    const int wn = (wid & 1) * 64;

    const int lr = lane >> 2;          // 0..15 row within 16-row chunk
    const int lc = (lane & 3) * 8;     // 0,8,16,24 elements within row
    const int r0 = 32 * wid;           // this wave's staging rows
    const __hip_bfloat16* Ag0 = xb  + (size_t)(bm + r0 + lr) * Cn + lc;
    const __hip_bfloat16* Ag1 = xb  + (size_t)(bm + r0 + 16 + lr) * Cn + lc;
    const __hip_bfloat16* Bg0 = wab + (size_t)(bn + r0 + lr) * Cn + lc;
    const __hip_bfloat16* Bg1 = wab + (size_t)(bn + r0 + 16 + lr) * Cn + lc;
    const int lbase0 = r0 * 32 + lane * 8;         // lds element offsets
    const int lbase1 = (r0 + 16) * 32 + lane * 8;

    const f32x4 zero = {0.f, 0.f, 0.f, 0.f};
    f32x4 acc[4][4];
#pragma unroll
    for (int i = 0; i < 4; ++i)
#pragma unroll
        for (int j = 0; j < 4; ++j) acc[i][j] = zero;

    stage16(Ag0, &As[0][lbase0]);
    stage16(Ag1, &As[0][lbase1]);
    stage16(Bg0, &Bs[0][lbase0]);
    stage16(Bg1, &Bs[0][lbase1]);
    __syncthreads();

    for (int kt = 0; kt < NKT; ++kt) {
        const int cur = kt & 1;
        if (kt + 1 < NKT) {
            const int kn = (kt + 1) * 32;
            stage16(Ag0 + kn, &As[cur ^ 1][lbase0]);
            stage16(Ag1 + kn, &As[cur ^ 1][lbase1]);
            stage16(Bg0 + kn, &Bs[cur ^ 1][lbase0]);
            stage16(Bg1 + kn, &Bs[cur ^ 1][lbase1]);
        }
        bf16x8 af[4], bfr[4];
#pragma unroll
        for (int i = 0; i < 4; ++i)
            af[i] = load8(&As[cur][(wm + i * 16 + l16) * 32 + quad * 8]);
#pragma unroll
        for (int j = 0; j < 4; ++j)
            bfr[j] = load8(&Bs[cur][(wn + j * 16 + l16) * 32 + quad * 8]);
#pragma unroll
        for (int i = 0; i < 4; ++i)
#pragma unroll
            for (int j = 0; j < 4; ++j)
                acc[i][j] = mfma16x16(af[i], bfr[j], acc[i][j]);
        __syncthreads();   // drains prefetch (vmcnt) + cur reads
    }

#pragma unroll
    for (int j = 0; j < 4; ++j) {
        const int n = bn + wn + j * 16 + l16;
        const float bv = bias[n];
        const int sel = n >> 11;      // 0=q, 1=k, 2=v
        const int c   = n & 2047;
        const int h   = c >> 7;
        const int d   = c & 127;
#pragma unroll
        for (int i = 0; i < 4; ++i) {
#pragma unroll
            for (int r = 0; r < 4; ++r) {
                const int m = bm + wm + i * 16 + quad * 4 + r;
                const int b = m >> 11;
                const int t = m & 2047;
                const int bh = b * Hn + h;
                const __hip_bfloat16 hv = __float2bfloat16(acc[i][j][r] + bv);
                if (sel == 0)      Qo[((size_t)bh * Tn + t) * Dn + d] = hv;
                else if (sel == 1) Ko[((size_t)bh * Tn + t) * Dn + d] = hv;
                else               Vt[((size_t)bh * Dn + d) * Tn + t] = hv;
            }
        }
    }
}

// ---------------------------------------------------------------------------
// RoPE in place on Q and K.
// ---------------------------------------------------------------------------
__global__ __launch_bounds__(256) void rope_kernel(
    __hip_bfloat16* __restrict__ Qo,
    __hip_bfloat16* __restrict__ Ko)
{
    const size_t idx = (size_t)blockIdx.x * blockDim.x + threadIdx.x; // BH*T*64
    const int d2 = (int)(idx & 63);
    const int t  = (int)((idx >> 6) & (size_t)(Tn - 1));
    const float inv = exp2f(-(float)d2 * (1.0f / 64.0f) * 13.287712379549449f);
    float sn, cs;
    sincosf((float)t * inv, &sn, &cs);
    const size_t base = (idx >> 6) * (size_t)Dn + (size_t)(2 * d2);
    {
        const float a = __bfloat162float(Qo[base]);
        const float b = __bfloat162float(Qo[base + 1]);
        Qo[base]     = __float2bfloat16(a * cs - b * sn);
        Qo[base + 1] = __float2bfloat16(a * sn + b * cs);
    }
    {
        const float a = __bfloat162float(Ko[base]);
        const float b = __bfloat162float(Ko[base + 1]);
        Ko[base]     = __float2bfloat16(a * cs - b * sn);
        Ko[base + 1] = __float2bfloat16(a * sn + b * cs);
    }
}

// ---------------------------------------------------------------------------
// Flash attention (causal). THIS ROUND: K/V staging switched from
// register-roundtrip (load8 -> ds_write, vmcnt(0) exposed at every tile top)
// to async global_load_lds with linear LDS + XOR-swizzled reads and
// inverse-pre-swizzled global sources (rule 21, both-sides-or-neither).
//   K tile [32][128] bf16, swizzle: col-seg ^= row&15   (conflict-free)
//   V^T tile [128][32] bf16, swizzle: col-seg ^= (row>>1)&3  (2-way = free)
// Prefetch for kt+1 issues BEFORE compute of kt; the single per-tile
// __syncthreads drains vmcnt after a full tile of MFMA (m97 pattern).
// ---------------------------------------------------------------------------
__global__ __launch_bounds__(256) void flash_kernel(
    const __hip_bfloat16* __restrict__ Qo,
    const __hip_bfloat16* __restrict__ Ko,
    const __hip_bfloat16* __restrict__ Vt,
    __hip_bfloat16* __restrict__ Y)
{
    __shared__ __align__(16) short Ks[2][32 * 128];  // 2 x 8 KB, swizzled
    __shared__ __align__(16) short Vs[2][128 * 32];  // 2 x 8 KB, swizzled
    __shared__ __align__(16) short Ps[4][16 * 40];   // 5 KB wave-private P
    const int tid  = threadIdx.x;
    const int lane = tid & 63;
    const int wid  = tid >> 6;
    const int quad = lane >> 4;
    const int l16  = lane & 15;
    const int bh   = blockIdx.x & (BH - 1);
    const int qblk = 31 - (blockIdx.x >> 5);         // heavy q-blocks first
    const int q0w  = qblk * 64 + wid * 16;
    const int nkt  = 2 * qblk + 2;

    const __hip_bfloat16* Qb = Qo + (size_t)bh * Tn * Dn;
    const __hip_bfloat16* Kg = Ko + (size_t)bh * Tn * Dn;   // [t][d]
    const __hip_bfloat16* Vg = Vt + (size_t)bh * Dn * Tn;   // [d][t]
    short* P = &Ps[wid][0];

    // --- staging geometry (dest seg = tid, tid+256; 16B segs) ---
    // K: dest seg i -> row r=i>>4, slot s=i&15; holds global (r, s^(r&15)).
    const int kr = tid >> 4;                 // 0..15 (call B: +16, same key)
    const int ksl = (tid & 15) ^ kr;         // pre-swizzled source col-seg
    const __hip_bfloat16* KgA = Kg + (size_t)kr * Dn + ksl * 8;
    // V: dest seg i -> row r=i>>2, slot s=i&3; holds global (r, s^((r>>1)&3)).
    const int vr = tid >> 2;                 // 0..63 (call B: +64, same key)
    const int vsl = (tid & 3) ^ ((vr >> 1) & 3);
    const __hip_bfloat16* VgA = Vg + (size_t)vr * Tn + vsl * 8;

    // --- swizzled read offsets (bytes), kt-invariant ---
    int koff[4];                             // kf0; kf1 = +4096
#pragma unroll
    for (int ks = 0; ks < 4; ++ks)
        koff[ks] = l16 * 256 + ((((ks * 4 + quad) ^ l16) & 15) << 4);
    const int vkey = ((quad ^ ((l16 >> 1) & 3)) << 4);   // j-independent

    bf16x8 qf[4];
#pragma unroll
    for (int ks = 0; ks < 4; ++ks)
        qf[ks] = load8(Qb + (size_t)(q0w + l16) * Dn + ks * 32 + quad * 8);

    const f32x4 zero = {0.f, 0.f, 0.f, 0.f};
    f32x4 o[8];
#pragma unroll
    for (int j = 0; j < 8; ++j) o[j] = zero;
    float lpart[4] = {0.f, 0.f, 0.f, 0.f};
    const float scale2 = 0.12751743430267602f;   // log2(e)/sqrt(128)

    // Prologue: stage tile 0 into buffer 0.
    stage16(KgA,            (__hip_bfloat16*)&Ks[0][tid * 8]);
    stage16(KgA + 16 * Dn,  (__hip_bfloat16*)&Ks[0][2048 + tid * 8]);
    stage16(VgA,            (__hip_bfloat16*)&Vs[0][tid * 8]);
    stage16(VgA + 64 * Tn,  (__hip_bfloat16*)&Vs[0][2048 + tid * 8]);
    __syncthreads();

    for (int kt = 0; kt < nkt; ++kt) {
        const int cur = kt & 1;
        if (kt + 1 < nkt) {
            const int kb2 = (kt + 1) * 32;
            const int nxt = cur ^ 1;
            stage16(KgA + (size_t)kb2 * Dn,           (__hip_bfloat16*)&Ks[nxt][tid * 8]);
            stage16(KgA + (size_t)(kb2 + 16) * Dn,    (__hip_bfloat16*)&Ks[nxt][2048 + tid * 8]);
            stage16(VgA + kb2,                        (__hip_bfloat16*)&Vs[nxt][tid * 8]);
            stage16(VgA + 64 * Tn + kb2,              (__hip_bfloat16*)&Vs[nxt][2048 + tid * 8]);
        }
        const int kb = kt * 32;
        if (kb <= q0w + 15) {
            f32x4 sc0 = zero, sc1 = zero;
#pragma unroll
            for (int ks = 0; ks < 4; ++ks) {
                bf16x8 kf0 = lds8(&Ks[cur][0], koff[ks]);
                bf16x8 kf1 = lds8(&Ks[cur][0], koff[ks] + 4096);
                sc0 = mfma16x16(qf[ks], kf0, sc0);
                sc1 = mfma16x16(qf[ks], kf1, sc1);
            }
            if (kb + 31 <= q0w) {
#pragma unroll
                for (int r = 0; r < 4; ++r) {
                    const float p0 = exp2f(sc0[r] * scale2);
                    const float p1 = exp2f(sc1[r] * scale2);
                    lpart[r] += p0 + p1;
                    P[(quad * 4 + r) * 40 + l16]      = bf16bits(p0);
                    P[(quad * 4 + r) * 40 + 16 + l16] = bf16bits(p1);
                }
            } else {
#pragma unroll
                for (int r = 0; r < 4; ++r) {
                    const int row = q0w + quad * 4 + r;
                    const float a0 = (kb + l16      <= row) ? sc0[r] * scale2 : -INFINITY;
                    const float a1 = (kb + 16 + l16 <= row) ? sc1[r] * scale2 : -INFINITY;
                    const float p0 = exp2f(a0);
                    const float p1 = exp2f(a1);
                    lpart[r] += p0 + p1;
                    P[(quad * 4 + r) * 40 + l16]      = bf16bits(p0);
                    P[(quad * 4 + r) * 40 + 16 + l16] = bf16bits(p1);
                }
            }
            __builtin_amdgcn_sched_barrier(0);
            const bf16x8 af = *(const bf16x8*)(P + l16 * 40 + quad * 8);
#pragma unroll
            for (int j = 0; j < 8; ++j) {
                bf16x8 vf = lds8(&Vs[cur][0], (j * 16 + l16) * 64 + vkey);
                o[j] = mfma16x16(af, vf, o[j]);
            }
            __builtin_amdgcn_sched_barrier(0);
        }
        __syncthreads();   // drains prefetch vmcnt + cur LDS reads
    }

    float invl[4];
#pragma unroll
    for (int r = 0; r < 4; ++r) {
        float s = lpart[r];
#pragma unroll
        for (int off = 1; off < 16; off <<= 1)
            s += __shfl_xor(s, off, 16);
        invl[r] = 1.0f / s;
    }

    const int b = bh >> 4;
    const int h = bh & 15;
#pragma unroll
    for (int j = 0; j < 8; ++j) {
#pragma unroll
        for (int r = 0; r < 4; ++r) {
            const int t = q0w + quad * 4 + r;
            Y[((size_t)b * Tn + t) * Cn + h * Dn + j * 16 + l16] =
                __float2bfloat16(o[j][r] * invl[r]);
        }
    }
}

// ---------------------------------------------------------------------------
// Output projection, pure bf16 inputs, global_load_lds staging, dbuf.
// out = Yb @ wpb^T + b_proj (fp32 out).
// ---------------------------------------------------------------------------
__global__ __launch_bounds__(256) void proj_gemm_kernel(
    const __hip_bfloat16* __restrict__ Yb,
    const __hip_bfloat16* __restrict__ wpb,
    const float* __restrict__ bias,
    float* __restrict__ out)
{
    __shared__ __align__(16) __hip_bfloat16 As[2][128 * 32];
    __shared__ __align__(16) __hip_bfloat16 Bs[2][128 * 32];
    const int tid  = threadIdx.x;
    const int lane = tid & 63;
    const int wid  = tid >> 6;
    const int quad = lane >> 4;
    const int l16  = lane & 15;
    const int bm = blockIdx.y * 128;
    const int bn = blockIdx.x * 128;
    const int wm = (wid >> 1) * 64;
    const int wn = (wid & 1) * 64;

    const int lr = lane >> 2;
    const int lc = (lane & 3) * 8;
    const int r0 = 32 * wid;
    const __hip_bfloat16* Ag0 = Yb  + (size_t)(bm + r0 + lr) * Cn + lc;
    const __hip_bfloat16* Ag1 = Yb  + (size_t)(bm + r0 + 16 + lr) * Cn + lc;
    const __hip_bfloat16* Bg0 = wpb + (size_t)(bn + r0 + lr) * Cn + lc;
    const __hip_bfloat16* Bg1 = wpb + (size_t)(bn + r0 + 16 + lr) * Cn + lc;
    const int lbase0 = r0 * 32 + lane * 8;
    const int lbase1 = (r0 + 16) * 32 + lane * 8;

    const f32x4 zero = {0.f, 0.f, 0.f, 0.f};
    f32x4 acc[4][4];
#pragma unroll
    for (int i = 0; i < 4; ++i)
#pragma unroll
        for (int j = 0; j < 4; ++j) acc[i][j] = zero;

    stage16(Ag0, &As[0][lbase0]);
    stage16(Ag1, &As[0][lbase1]);
    stage16(Bg0, &Bs[0][lbase0]);
    stage16(Bg1, &Bs[0][lbase1]);
    __syncthreads();

    for (int kt = 0; kt < NKT; ++kt) {
        const int cur = kt & 1;
        if (kt + 1 < NKT) {
            const int kn = (kt + 1) * 32;
            stage16(Ag0 + kn, &As[cur ^ 1][lbase0]);
            stage16(Ag1 + kn, &As[cur ^ 1][lbase1]);
            stage16(Bg0 + kn, &Bs[cur ^ 1][lbase0]);
            stage16(Bg1 + kn, &Bs[cur ^ 1][lbase1]);
        }
        bf16x8 af[4], bfr[4];
#pragma unroll
        for (int i = 0; i < 4; ++i)
            af[i] = load8(&As[cur][(wm + i * 16 + l16) * 32 + quad * 8]);
#pragma unroll
        for (int j = 0; j < 4; ++j)
            bfr[j] = load8(&Bs[cur][(wn + j * 16 + l16) * 32 + quad * 8]);
#pragma unroll
        for (int i = 0; i < 4; ++i)
#pragma unroll
            for (int j = 0; j < 4; ++j)
                acc[i][j] = mfma16x16(af[i], bfr[j], acc[i][j]);
        __syncthreads();
    }

#pragma unroll
    for (int j = 0; j < 4; ++j) {
        const int n = bn + wn + j * 16 + l16;
        const float bv = bias[n];
#pragma unroll
        for (int i = 0; i < 4; ++i) {
#pragma unroll
            for (int r = 0; r < 4; ++r) {
                const int m = bm + wm + i * 16 + quad * 4 + r;
                out[(size_t)m * Cn + n] = acc[i][j][r] + bv;   // fp32 store
            }
        }
    }
}

// ---------------------------------------------------------------------------
extern "C" void kernel_launch(void* const* d_in, const int* in_sizes, int n_in,
                              void* d_out, int out_size, void* d_ws, size_t ws_size,
                              hipStream_t stream)
{
    // All five inputs AND the output are fp32 (verified round 5).
    const float* x      = (const float*)d_in[0];
    const float* w_att  = (const float*)d_in[1];
    const float* b_att  = (const float*)d_in[2];
    const float* w_proj = (const float*)d_in[3];
    const float* b_proj = (const float*)d_in[4];
    float* out = (float*)d_out;

    // Workspace layout (bf16 elements), ~96 MB total:
    //   [Qo per][Ko per][Vt per][xb per | Yb alias][wab 12.58M][wpb 4.19M]
    // Yb aliases xb: xb is dead after qkv_gemm; flash writes Yb later
    // (stream-ordered), proj reads Yb + wpb.
    const size_t per  = (size_t)BH * Tn * Dn;        // 8,388,608
    const size_t wabN = (size_t)Nqkv * Cn;           // 12,582,912
    __hip_bfloat16* Qo  = (__hip_bfloat16*)d_ws;
    __hip_bfloat16* Ko  = Qo + per;
    __hip_bfloat16* Vt  = Ko + per;
    __hip_bfloat16* xb  = Vt + per;
    __hip_bfloat16* wab = xb + per;
    __hip_bfloat16* wpb = wab + wabN;
    __hip_bfloat16* Yb  = xb;                        // alias (see above)

    dim3 blk(256);
    cvt_kernel<<<dim3((Mrows * Cn) / 2048), blk, 0, stream>>>(x, xb);
    cvt_kernel<<<dim3((Nqkv * Cn) / 2048), blk, 0, stream>>>(w_att, wab);
    cvt_kernel<<<dim3((Cn * Cn) / 2048), blk, 0, stream>>>(w_proj, wpb);
    qkv_gemm_kernel<<<dim3(Nqkv / 128, Mrows / 128), blk, 0, stream>>>(
        xb, wab, b_att, Qo, Ko, Vt);
    rope_kernel<<<dim3((BH * Tn * 64) / 256), blk, 0, stream>>>(Qo, Ko);
    flash_kernel<<<dim3((Tn / 64) * BH), blk, 0, stream>>>(Qo, Ko, Vt, Yb);
    proj_gemm_kernel<<<dim3(Cn / 128, Mrows / 128), blk, 0, stream>>>(
        Yb, wpb, b_proj, out);
}